// Round 1
// 196.588 us; speedup vs baseline: 1.1231x; 1.1231x over previous
//
#include <hip/hip_runtime.h>
#include <math.h>

#define Bn 16
#define Hh 512
#define Ww 512
#define HW_ (Hh * Ww)
#define TILE 32
#define NTHREADS 1024
#define FP 36              // stride of input-halo / feat grids (36 wide)
#define SIN_N 1328         // staged input entries: 36*36=1296 + pad for tile overreach
#define NF 1248            // feat entries per half: NT1*32
#define NT1 39             // conv1 position tiles of 32

typedef __bf16 bfrag __attribute__((ext_vector_type(8)));
typedef __bf16 bf4   __attribute__((ext_vector_type(4)));
typedef float  ffrag __attribute__((ext_vector_type(16)));
typedef float  f32x2 __attribute__((ext_vector_type(2)));

__device__ __forceinline__ short f2bf(float f) {           // RNE fp32 -> bf16 bits
    unsigned u = __float_as_uint(f);
    unsigned r = u + 0x7FFFu + ((u >> 16) & 1u);
    return (short)(r >> 16);
}

__device__ __forceinline__ f32x2 mk2(float a, float b) { f32x2 t; t.x = a; t.y = b; return t; }

// gelu(x) ~= x*sigmoid(2*0.7978845608*(x+0.044715x^3)) via exp2
__device__ __forceinline__ f32x2 gelu_fast2(f32x2 x) {
    f32x2 z = x * x;
    f32x2 a = z * 0.044715f + 1.0f;
    f32x2 u = (x * 2.302208199f) * a;
    f32x2 e;
    e.x = __builtin_amdgcn_exp2f(u.x);
    e.y = __builtin_amdgcn_exp2f(u.y);
    f32x2 r;
    r.x = __builtin_amdgcn_rcpf(e.x + 1.0f);
    r.y = __builtin_amdgcn_rcpf(e.y + 1.0f);
    return x - x * r;                      // x * e/(e+1)
}

__device__ __forceinline__ float bilin(const float* __restrict__ img, float py, float px) {
    float y0f = floorf(py), x0f = floorf(px);
    float wy = py - y0f, wx = px - x0f;
    int y0 = (int)y0f, x0 = (int)x0f;
    auto corner = [&](int yi, int xi) -> float {
        bool valid = (yi >= 0) && (yi < Hh) && (xi >= 0) && (xi < Ww);
        int yc = min(max(yi, 0), Hh - 1);
        int xc = min(max(xi, 0), Ww - 1);
        float v = img[yc * Ww + xc];
        return valid ? v : 0.0f;
    };
    float v00 = corner(y0,     x0);
    float v01 = corner(y0,     x0 + 1);
    float v10 = corner(y0 + 1, x0);
    float v11 = corner(y0 + 1, x0 + 1);
    return (1.0f - wy) * ((1.0f - wx) * v00 + wx * v01) +
           wy          * ((1.0f - wx) * v10 + wx * v11);
}

// ---- pre-pass: pack w2 A-frags (9 taps) + w1 tap-pair A-frags (5 pairs) ----
// ws int4 [0,576)    : w2 frags: lane l31=co(m), elem j -> ci = lh*8+j, per tap
// ws int4 [576,896)  : w1 frags: lane l31=co(m), elem j -> c=j(<3), tap = 2*pair+lh
__global__ void pack_w(const float* __restrict__ w2, const float* __restrict__ w1,
                       int* __restrict__ ws) {
    const int lane = threadIdx.x;            // 64 threads
    const int l31  = lane & 31;
    const int lh   = lane >> 5;
    for (int tap = 0; tap < 9; ++tap) {
        int pk[4];
        #pragma unroll
        for (int jj = 0; jj < 4; ++jj) {
            float v0 = (l31 < 18) ? w2[(l31 * 16 + lh * 8 + 2 * jj    ) * 9 + tap] : 0.0f;
            float v1 = (l31 < 18) ? w2[(l31 * 16 + lh * 8 + 2 * jj + 1) * 9 + tap] : 0.0f;
            pk[jj] = ((int)(unsigned short)f2bf(v0)) | ((int)f2bf(v1) << 16);
        }
        ((int4*)ws)[tap * 64 + lane] = make_int4(pk[0], pk[1], pk[2], pk[3]);
    }
    for (int p = 0; p < 5; ++p) {
        int tap = 2 * p + lh;
        int pk[4];
        #pragma unroll
        for (int jj = 0; jj < 4; ++jj) {
            int j0 = 2 * jj, j1 = 2 * jj + 1;
            float v0 = (l31 < 16 && j0 < 3 && tap < 9) ? w1[l31 * 27 + j0 * 9 + tap] : 0.0f;
            float v1 = (l31 < 16 && j1 < 3 && tap < 9) ? w1[l31 * 27 + j1 * 9 + tap] : 0.0f;
            pk[jj] = ((int)(unsigned short)f2bf(v0)) | ((int)f2bf(v1) << 16);
        }
        ((int4*)ws)[576 + p * 64 + lane] = make_int4(pk[0], pk[1], pk[2], pk[3]);
    }
}

// LDS (no aliasing needed any more):
//   s_in16  bf16 [SIN_N][8]  @ 0          (21248 B)  input halo, 3 real ch + zero pad
//   s_feat  bf16 [2][NF][8]  @ 21248      (39936 B)  conv1 output (conv2 B-matrix)
#define SMEM_BYTES (SIN_N * 16 + 2 * NF * 16)   // 61184

__global__ __launch_bounds__(NTHREADS, 8) void residual_advection_fused(
    const float* __restrict__ pm25,   // (16,1,512,512)
    const float* __restrict__ wind,   // (16,2,512,512)
    const float* __restrict__ topo,   // (16,1,512,512)
    const float* __restrict__ b1,     // (16)
    const float* __restrict__ b2,     // (18)
    const float* __restrict__ wt,     // (9)
    const int*   __restrict__ wsB,    // packed w2 + w1 A-fragments
    float* __restrict__ out)          // (16,1,512,512)
{
    __shared__ __align__(16) char smem[SMEM_BYTES];
    __bf16* s_in16 = (__bf16*)smem;                  // [SIN_N][8]
    __bf16* s_feat = (__bf16*)(smem + SIN_N * 16);   // [2][NF][8]

    const int tid = threadIdx.x;
    const int bb  = blockIdx.z;
    const int ty0 = blockIdx.y * TILE;
    const int tx0 = blockIdx.x * TILE;

    const int lane = tid & 63;
    const int wv   = tid >> 6;       // 0..15
    const int l31  = lane & 31;
    const int lh   = lane >> 5;

    const bfrag* WF = (const bfrag*)wsB;

    // hoist conv1 weight A-frags (global, L2-hot; latency hidden under staging)
    bfrag wa[5];
    #pragma unroll
    for (int p = 0; p < 5; ++p) wa[p] = WF[576 + p * 64 + lane];

    // ---- P1: stage 36x36 input halo as bf16 [pos][8] (zero outside image) ----
    for (int idx = tid; idx < SIN_N; idx += NTHREADS) {
        float c0 = 0.0f, c1 = 0.0f, c2 = 0.0f;
        if (idx < 1296) {
            int r = idx / FP, c = idx - r * FP;
            int gy = ty0 - 2 + r, gx = tx0 - 2 + c;
            if ((unsigned)gy < (unsigned)Hh && (unsigned)gx < (unsigned)Ww) {
                int g = gy * Ww + gx;
                c0 = wind[(bb * 2 + 0) * HW_ + g];
                c1 = wind[(bb * 2 + 1) * HW_ + g];
                c2 = topo[bb * HW_ + g];
            }
        }
        bfrag v;
        v[0] = (__bf16)c0; v[1] = (__bf16)c1; v[2] = (__bf16)c2; v[3] = (__bf16)0.0f;
        v[4] = (__bf16)0.0f; v[5] = (__bf16)0.0f; v[6] = (__bf16)0.0f; v[7] = (__bf16)0.0f;
        *(bfrag*)&s_in16[idx * 8] = v;
    }
    __syncthreads();

    // ---- P2: conv1 via MFMA, A=w1 (m=co), B=input (n=pos), 2 taps per K=16 ----
    {
        int off1[5];
        #pragma unroll
        for (int p = 0; p < 5; ++p) {
            int t0 = 2 * p, t1 = (2 * p + 1 < 9) ? 2 * p + 1 : 0;  // p=4,lh=1: A-half is zero
            int o0 = (t0 / 3) * FP + t0 % 3;
            int o1 = (t1 / 3) * FP + t1 % 3;
            off1[p] = lh ? o1 : o0;
        }
        const float4 ba  = *(const float4*)&b1[4 * lh];        // co 0..3 / 4..7
        const float4 bb4 = *(const float4*)&b1[8 + 4 * lh];    // co 8..11 / 12..15

        for (int tt = wv; tt < NT1; tt += 16) {
            const int m0 = tt * 32 + l31;
            ffrag acc;
            #pragma unroll
            for (int r = 0; r < 16; ++r) acc[r] = 0.0f;
            #pragma unroll
            for (int p = 0; p < 5; ++p) {
                bfrag bx = *(const bfrag*)&s_in16[(m0 + off1[p]) * 8];
                acc = __builtin_amdgcn_mfma_f32_32x32x16_bf16(wa[p], bx, acc, 0, 0, 0);
            }
            // epilogue: bias + gelu + image-validity mask (conv2 zero padding), bf16 store
            int fyp = m0 / FP;
            int fxp = m0 - fyp * FP;
            int gy = ty0 + fyp - 1, gx = tx0 + fxp - 1;
            float msk = ((unsigned)gy < (unsigned)Hh && (unsigned)gx < (unsigned)Ww) ? 1.0f : 0.0f;
            f32x2 g0 = gelu_fast2(mk2(acc[0] + ba.x,  acc[1] + ba.y))  * msk;
            f32x2 g1 = gelu_fast2(mk2(acc[2] + ba.z,  acc[3] + ba.w))  * msk;
            f32x2 g2 = gelu_fast2(mk2(acc[4] + bb4.x, acc[5] + bb4.y)) * msk;
            f32x2 g3 = gelu_fast2(mk2(acc[6] + bb4.z, acc[7] + bb4.w)) * msk;
            bf4 wlo, whi;
            wlo[0] = (__bf16)g0.x; wlo[1] = (__bf16)g0.y; wlo[2] = (__bf16)g1.x; wlo[3] = (__bf16)g1.y;
            whi[0] = (__bf16)g2.x; whi[1] = (__bf16)g2.y; whi[2] = (__bf16)g3.x; whi[3] = (__bf16)g3.y;
            *(bf4*)&s_feat[m0 * 8 + lh * 4]        = wlo;   // ch (4lh..4lh+3)   -> half 0
            *(bf4*)&s_feat[(NF + m0) * 8 + lh * 4] = whi;   // ch (8+4lh..11+4lh)-> half 1
        }
    }
    __syncthreads();

    // ---- P3: conv2 via MFMA, A=w2 (m=co), B=feat (n=pixel) ----
    ffrag a0, a1;
    #pragma unroll
    for (int r = 0; r < 16; ++r) { a0[r] = 0.0f; a1[r] = 0.0f; }
    {
        const int base0 = (2 * wv) * FP + l31;     // feat idx of pixel (2wv, l31)
        #pragma unroll
        for (int t = 0; t < 9; ++t) {
            const int toff = (t / 3) * FP + (t % 3);
            bfrag wf = WF[t * 64 + lane];
            bfrag f0 = *(const bfrag*)&s_feat[(lh * NF + base0 + toff) * 8];
            bfrag f1 = *(const bfrag*)&s_feat[(lh * NF + base0 + FP + toff) * 8];
            a0 = __builtin_amdgcn_mfma_f32_32x32x16_bf16(wf, f0, a0, 0, 0, 0);
            a1 = __builtin_amdgcn_mfma_f32_32x32x16_bf16(wf, f1, a1, 0, 0, 0);
        }
    }

    // ---- P4: deformable sampling straight from accumulator registers ----
    // C/D: col = pixel = l31, row = co. Lane half lh=0 holds taps {0,1,4,5,8}
    // (regs (2i,2i+1) = co {0,1|2,3|8,9|10,11|16,17}); lh=1 holds taps {2,3,6,7}.
    {
        const float* img = pm25 + bb * HW_;
        const float fy0 = (float)(ty0 + 2 * wv);
        const float fx  = (float)(tx0 + l31);
        float o0 = 0.0f, o1 = 0.0f;
        constexpr int T0[5] = {0, 1, 4, 5, 8};
        constexpr int T1[5] = {2, 3, 6, 7, 0};
        #pragma unroll
        for (int i = 0; i < 5; ++i) {
            const int t0 = T0[i], t1 = T1[i];
            float wk  = lh ? ((i < 4) ? wt[t1] : 0.0f) : wt[t0];   // wave-uniform loads, per-half select
            float bdy = lh ? b2[2 * t1]     : b2[2 * t0];
            float bdx = lh ? b2[2 * t1 + 1] : b2[2 * t0 + 1];
            float kdy = lh ? (float)(t1 / 3 - 1) : (float)(t0 / 3 - 1);
            float kdx = lh ? (float)(t1 % 3 - 1) : (float)(t0 % 3 - 1);
            if (wk != 0.0f) {                 // per-lane exec mask; skips zero taps
                float dy0 = a0[2 * i] + bdy, dx0 = a0[2 * i + 1] + bdx;
                float dy1 = a1[2 * i] + bdy, dx1 = a1[2 * i + 1] + bdx;
                o0 += wk * bilin(img, fy0 + kdy + dy0,        fx + kdx + dx0);
                o1 += wk * bilin(img, fy0 + 1.0f + kdy + dy1, fx + kdx + dx1);
            }
        }
        o0 += __shfl_xor(o0, 32);             // combine the two tap-halves per pixel
        o1 += __shfl_xor(o1, 32);
        float ov = lh ? o1 : o0;              // lh0 stores row 2wv, lh1 stores row 2wv+1
        out[bb * HW_ + (ty0 + 2 * wv + lh) * Ww + (tx0 + l31)] = ov;
    }
}

extern "C" void kernel_launch(void* const* d_in, const int* in_sizes, int n_in,
                              void* d_out, int out_size, void* d_ws, size_t ws_size,
                              hipStream_t stream) {
    const float* pm25 = (const float*)d_in[0];
    const float* wind = (const float*)d_in[1];
    const float* topo = (const float*)d_in[2];
    const float* w1   = (const float*)d_in[3];
    const float* b1   = (const float*)d_in[4];
    const float* w2   = (const float*)d_in[5];
    const float* b2   = (const float*)d_in[6];
    const float* wt   = (const float*)d_in[7];
    float* o          = (float*)d_out;
    int*   wsB        = (int*)d_ws;   // 9216 B w2-frags + 5120 B w1-frags = 14336 B

    pack_w<<<dim3(1), dim3(64), 0, stream>>>(w2, w1, wsB);

    dim3 grid(Ww / TILE, Hh / TILE, Bn);
    residual_advection_fused<<<grid, dim3(NTHREADS), 0, stream>>>(
        pm25, wind, topo, b1, b2, wt, wsB, o);
}

// Round 2
// 176.844 us; speedup vs baseline: 1.2484x; 1.1116x over previous
//
#include <hip/hip_runtime.h>
#include <math.h>

#define Bn 16
#define Hh 512
#define Ww 512
#define HW_ (Hh * Ww)
#define TILE 32
#define NTHREADS 1024
#define S 37                 // unified grid stride (input halo & feat grids)
#define SIN_N 1400           // staged input positions (36*37=1332 valid + ky3 pad rows)
#define NFP 1280             // feat positions per 8-ch half (80 tiles * 16)
#define NT2 80               // conv1 position tiles of 16

typedef __bf16 bfrag __attribute__((ext_vector_type(8)));
typedef __bf16 bf4   __attribute__((ext_vector_type(4)));
typedef float  ffrag __attribute__((ext_vector_type(16)));
typedef float  f32x4 __attribute__((ext_vector_type(4)));
typedef float  f32x2 __attribute__((ext_vector_type(2)));

__device__ __forceinline__ short f2bf(float f) {           // RNE fp32 -> bf16 bits
    unsigned u = __float_as_uint(f);
    unsigned r = u + 0x7FFFu + ((u >> 16) & 1u);
    return (short)(r >> 16);
}

__device__ __forceinline__ f32x2 mk2(float a, float b) { f32x2 t; t.x = a; t.y = b; return t; }

// gelu(x) ~= x*sigmoid(2*0.7978845608*(x+0.044715x^3)) via exp2
__device__ __forceinline__ f32x2 gelu_fast2(f32x2 x) {
    f32x2 z = x * x;
    f32x2 a = z * 0.044715f + 1.0f;
    f32x2 u = (x * 2.302208199f) * a;
    f32x2 e;
    e.x = __builtin_amdgcn_exp2f(u.x);
    e.y = __builtin_amdgcn_exp2f(u.y);
    f32x2 r;
    r.x = __builtin_amdgcn_rcpf(e.x + 1.0f);
    r.y = __builtin_amdgcn_rcpf(e.y + 1.0f);
    return x - x * r;                      // x * e/(e+1)
}

__device__ __forceinline__ float bilin(const float* __restrict__ img, float py, float px) {
    float y0f = floorf(py), x0f = floorf(px);
    float wy = py - y0f, wx = px - x0f;
    int y0 = (int)y0f, x0 = (int)x0f;
    int yc0 = min(max(y0, 0), Hh - 1), yc1 = min(max(y0 + 1, 0), Hh - 1);
    int xc0 = min(max(x0, 0), Ww - 1), xc1 = min(max(x0 + 1, 0), Ww - 1);
    bool vy0 = (unsigned)y0 < (unsigned)Hh, vy1 = (unsigned)(y0 + 1) < (unsigned)Hh;
    bool vx0 = (unsigned)x0 < (unsigned)Ww, vx1 = (unsigned)(x0 + 1) < (unsigned)Ww;
    const float* r0 = img + yc0 * Ww;
    const float* r1 = img + yc1 * Ww;
    float v00 = (vy0 && vx0) ? r0[xc0] : 0.0f;
    float v01 = (vy0 && vx1) ? r0[xc1] : 0.0f;
    float v10 = (vy1 && vx0) ? r1[xc0] : 0.0f;
    float v11 = (vy1 && vx1) ? r1[xc1] : 0.0f;
    return (1.0f - wy) * ((1.0f - wx) * v00 + wx * v01) +
           wy          * ((1.0f - wx) * v10 + wx * v11);
}

// ---- pre-pass: pack w2 A-frags (9 taps, 32x32x16) + w1 A-frags (2, 16x16x32) ----
// ws int4 [0,576)   : w2 frags: lane l31=co(m), elem j -> ci = lh*8+j, per tap
// ws int4 [576,704) : w1 frags: lane m=lane&15(co), k=(lane>>4)*8+j,
//                     k = 16*kyloc + 4*kx + c, ky = 2*t + kyloc;
//                     value = w1[co][c][ky][kx] (kx<3,c<3,ky<3); slot t=0,k=3 = b1[co]
__global__ void pack_w(const float* __restrict__ w2, const float* __restrict__ w1,
                       const float* __restrict__ b1, int* __restrict__ ws) {
    const int lane = threadIdx.x;            // 64 threads
    const int l31  = lane & 31;
    const int lh   = lane >> 5;
    for (int tap = 0; tap < 9; ++tap) {
        int pk[4];
        #pragma unroll
        for (int jj = 0; jj < 4; ++jj) {
            float v0 = (l31 < 18) ? w2[(l31 * 16 + lh * 8 + 2 * jj    ) * 9 + tap] : 0.0f;
            float v1 = (l31 < 18) ? w2[(l31 * 16 + lh * 8 + 2 * jj + 1) * 9 + tap] : 0.0f;
            pk[jj] = ((int)(unsigned short)f2bf(v0)) | ((int)f2bf(v1) << 16);
        }
        ((int4*)ws)[tap * 64 + lane] = make_int4(pk[0], pk[1], pk[2], pk[3]);
    }
    const int m  = lane & 15;
    const int kq = lane >> 4;
    for (int t = 0; t < 2; ++t) {
        int pk[4];
        #pragma unroll
        for (int jj = 0; jj < 4; ++jj) {
            float vv[2];
            #pragma unroll
            for (int h = 0; h < 2; ++h) {
                int k   = kq * 8 + 2 * jj + h;
                int kyl = k >> 4, kx = (k >> 2) & 3, c = k & 3;
                int ky  = 2 * t + kyl;
                float x = 0.0f;
                if (kx < 3 && c < 3 && ky < 3) x = w1[m * 27 + c * 9 + ky * 3 + kx];
                if (t == 0 && k == 3) x = b1[m];     // bias slot (reads const-1.0 channel)
                vv[h] = x;
            }
            pk[jj] = ((int)(unsigned short)f2bf(vv[0])) | ((int)f2bf(vv[1]) << 16);
        }
        ((int4*)ws)[576 + t * 64 + lane] = make_int4(pk[0], pk[1], pk[2], pk[3]);
    }
}

// LDS:
//   s_in   bf16 dup-entries [SIN_N][8] @ 0      (22400 B)
//          entry e (16B) = positions e,e+1, each (wind0,wind1,topo,1.0) bf16
//   s_feat bf16 [2][NFP][8] @ 22400             (40960 B)  conv1 out (conv2 B-matrix)
#define SMEM_BYTES (SIN_N * 16 + 2 * NFP * 16)   // 63360

__global__ __launch_bounds__(NTHREADS, 8) void residual_advection_fused(
    const float* __restrict__ pm25,   // (16,1,512,512)
    const float* __restrict__ wind,   // (16,2,512,512)
    const float* __restrict__ topo,   // (16,1,512,512)
    const float* __restrict__ b2,     // (18)
    const float* __restrict__ wt,     // (9)
    const int*   __restrict__ wsB,    // packed w2 + w1 A-fragments
    float* __restrict__ out)          // (16,1,512,512)
{
    __shared__ __align__(16) char smem[SMEM_BYTES];
    __bf16* s_in   = (__bf16*)smem;                  // dup entries, 16B each
    __bf16* s_feat = (__bf16*)(smem + SIN_N * 16);   // [2][NFP][8]

    const int tid = threadIdx.x;
    const int bb  = blockIdx.z;
    const int ty0 = blockIdx.y * TILE;
    const int tx0 = blockIdx.x * TILE;
    const bool edge = (ty0 == 0) || (ty0 == Hh - TILE) || (tx0 == 0) || (tx0 == Ww - TILE);

    const int lane = tid & 63;
    const int wv   = tid >> 6;       // 0..15
    const int l31  = lane & 31;
    const int lh   = lane >> 5;

    const bfrag* WF = (const bfrag*)wsB;

    // hoist conv1 weight A-frags (L2-hot; latency hidden under staging)
    bfrag w1f0 = WF[576 + lane];
    bfrag w1f1 = WF[640 + lane];

    // ---- P1: stage input halo, dup layout: pos idx -> entry[idx].lo, entry[idx-1].hi ----
    for (int idx = tid; idx < SIN_N; idx += NTHREADS) {
        float c0 = 0.0f, c1 = 0.0f, c2 = 0.0f;
        if (idx < 36 * S) {
            int r = idx / S, c = idx - r * S;
            int gy = ty0 - 2 + r, gx = tx0 - 2 + c;
            if ((unsigned)gy < (unsigned)Hh && (unsigned)gx < (unsigned)Ww) {
                int g = gy * Ww + gx;
                c0 = wind[(bb * 2 + 0) * HW_ + g];
                c1 = wind[(bb * 2 + 1) * HW_ + g];
                c2 = topo[bb * HW_ + g];
            }
        }
        bf4 v;
        v[0] = (__bf16)c0; v[1] = (__bf16)c1; v[2] = (__bf16)c2; v[3] = (__bf16)1.0f;
        *(bf4*)&s_in[idx * 8] = v;                       // entry idx, low 8B
        if (idx > 0) *(bf4*)&s_in[idx * 8 - 4] = v;      // entry idx-1, high 8B
    }
    __syncthreads();

    // ---- P2: conv1 via MFMA 16x16x32, A=w1 (m=co16), B=input rows (n=pos) ----
    // K = 2 kernel-rows x (4 kx x 4 ch); bias via const-1.0 channel slot.
    {
        const int n    = lane & 15;
        const int kq   = lane >> 4;
        const int qoff = (kq >> 1) * S + (kq & 1) * 2;   // kyloc row + kx-pair offset
        #pragma unroll
        for (int i = 0; i < 5; ++i) {
            const int p = (wv * 5 + i) * 16 + n;
            f32x4 acc;
            acc[0] = 0.0f; acc[1] = 0.0f; acc[2] = 0.0f; acc[3] = 0.0f;
            bfrag bx0 = *(const bfrag*)&s_in[(p + qoff) * 8];           // ky rows 0,1
            bfrag bx1 = *(const bfrag*)&s_in[(p + qoff + 2 * S) * 8];   // ky rows 2,(pad)
            acc = __builtin_amdgcn_mfma_f32_16x16x32_bf16(w1f0, bx0, acc, 0, 0, 0);
            acc = __builtin_amdgcn_mfma_f32_16x16x32_bf16(w1f1, bx1, acc, 0, 0, 0);
            // epilogue: gelu + (edge-only) validity mask, bf16 store of 4 co values
            f32x2 g0 = gelu_fast2(mk2(acc[0], acc[1]));
            f32x2 g1 = gelu_fast2(mk2(acc[2], acc[3]));
            if (edge) {
                int fy = p / S;
                int fx = p - fy * S;
                int gy = ty0 + fy - 1, gx = tx0 + fx - 1;
                float msk = ((unsigned)gy < (unsigned)Hh && (unsigned)gx < (unsigned)Ww)
                            ? 1.0f : 0.0f;
                g0 *= msk; g1 *= msk;
            }
            bf4 w4;
            w4[0] = (__bf16)g0.x; w4[1] = (__bf16)g0.y;
            w4[2] = (__bf16)g1.x; w4[3] = (__bf16)g1.y;
            // co-group kq: half = kq>>1, sub-slot = kq&1
            *(bf4*)&s_feat[((kq >> 1) * NFP + p) * 8 + (kq & 1) * 4] = w4;
        }
    }
    __syncthreads();

    // ---- P3: conv2 via MFMA 32x32x16, A=w2 (m=co18), B=feat (n=pixel) ----
    ffrag a0, a1;
    #pragma unroll
    for (int r = 0; r < 16; ++r) { a0[r] = 0.0f; a1[r] = 0.0f; }
    {
        const int vb = (lh * NFP + (2 * wv) * S + l31) * 8;
        #pragma unroll
        for (int t = 0; t < 9; ++t) {
            const int toff = ((t / 3) * S + (t % 3)) * 8;
            bfrag wf = WF[t * 64 + lane];
            bfrag f0 = *(const bfrag*)&s_feat[vb + toff];
            bfrag f1 = *(const bfrag*)&s_feat[vb + toff + S * 8];
            a0 = __builtin_amdgcn_mfma_f32_32x32x16_bf16(wf, f0, a0, 0, 0, 0);
            a1 = __builtin_amdgcn_mfma_f32_32x32x16_bf16(wf, f1, a1, 0, 0, 0);
        }
    }

    // ---- P4: lane-half exchange, then one bilinear sample per lane ----
    // C/D: col = pixel = l31, row = co = (reg&3)+8*(reg>>2)+4*lh.
    // lh0 holds rows {0-3,8-11,16,17}, lh1 holds rows {4-7,12-15}; exchange the
    // complements so each lane owns all 18 rows for pixel-row (2wv+lh).
    {
        float ex[10];
        #pragma unroll
        for (int j = 0; j < 10; ++j) {
            float snd = lh ? a0[(j < 8) ? j : 7] : a1[j];
            ex[j] = __shfl_xor(snd, 32);
        }
        auto getv = [&](int row) -> float {          // row is compile-time constant
            if ((row & 4) == 0) {                    // rows 0-3,8-11,16,17
                int r = (row < 8) ? row : ((row < 16) ? row - 4 : row - 8);
                return lh ? ex[r] : a0[r];
            } else {                                 // rows 4-7,12-15
                int r = (row & 3) + 4 * (row >> 3);
                return lh ? a1[r] : ex[r];
            }
        };
        const float* img = pm25 + bb * HW_;
        const int py_i = ty0 + 2 * wv + lh;
        const int px_i = tx0 + l31;
        const float fy = (float)py_i, fx = (float)px_i;
        float o = 0.0f;
        #pragma unroll
        for (int t = 0; t < 9; ++t) {
            float wk = wt[t];                        // uniform -> scalar branch
            if (wk != 0.0f) {
                float dy = getv(2 * t)     + b2[2 * t];
                float dx = getv(2 * t + 1) + b2[2 * t + 1];
                float py = fy + (float)(t / 3 - 1) + dy;
                float px = fx + (float)(t % 3 - 1) + dx;
                o += wk * bilin(img, py, px);
            }
        }
        out[bb * HW_ + py_i * Ww + px_i] = o;
    }
}

extern "C" void kernel_launch(void* const* d_in, const int* in_sizes, int n_in,
                              void* d_out, int out_size, void* d_ws, size_t ws_size,
                              hipStream_t stream) {
    const float* pm25 = (const float*)d_in[0];
    const float* wind = (const float*)d_in[1];
    const float* topo = (const float*)d_in[2];
    const float* w1   = (const float*)d_in[3];
    const float* b1   = (const float*)d_in[4];
    const float* w2   = (const float*)d_in[5];
    const float* b2   = (const float*)d_in[6];
    const float* wt   = (const float*)d_in[7];
    float* o          = (float*)d_out;
    int*   wsB        = (int*)d_ws;   // 576+128 int4 = 11264 B

    pack_w<<<dim3(1), dim3(64), 0, stream>>>(w2, w1, b1, wsB);

    dim3 grid(Ww / TILE, Hh / TILE, Bn);
    residual_advection_fused<<<grid, dim3(NTHREADS), 0, stream>>>(
        pm25, wind, topo, b2, wt, wsB, o);
}

// Round 3
// 176.806 us; speedup vs baseline: 1.2487x; 1.0002x over previous
//
#include <hip/hip_runtime.h>
#include <math.h>

#define Bn 16
#define Hh 512
#define Ww 512
#define HW_ (Hh * Ww)
#define TILE 32
#define NTHREADS 1024
#define S 37                 // unified grid stride (input halo & feat grids)
#define SIN_N 1400           // staged input positions (36*37=1332 valid + pad rows)
#define NFP 1280             // feat positions per 8-ch half (80 tiles * 16)
#define NT2 80               // conv1 position tiles of 16

typedef __bf16 bfrag __attribute__((ext_vector_type(8)));
typedef __bf16 bf4   __attribute__((ext_vector_type(4)));
typedef float  ffrag __attribute__((ext_vector_type(16)));
typedef float  f32x4 __attribute__((ext_vector_type(4)));
typedef float  f32x2 __attribute__((ext_vector_type(2)));

__device__ __forceinline__ short f2bf(float f) {           // RNE fp32 -> bf16 bits
    unsigned u = __float_as_uint(f);
    unsigned r = u + 0x7FFFu + ((u >> 16) & 1u);
    return (short)(r >> 16);
}

__device__ __forceinline__ f32x2 mk2(float a, float b) { f32x2 t; t.x = a; t.y = b; return t; }

// gelu exact-form via trans-free erf polynomial:
// gelu(x) = 0.5x(1+erf(x/sqrt2)); erf(y) ~= t*P(t^2), t = clamp(y,-2.5,2.5).
// P = Newton interpolation of erf(sqrt(u))/sqrt(u) at Chebyshev nodes on u in [0,6.25];
// |erf err| <~ 2.8e-3 (tail clamp overshoot 2.4e-3); rel feat err <= bf16 quant level.
__device__ __forceinline__ f32x2 gelu_fast2(f32x2 x) {
    const float C0 = 1.1259890f, C1 = -0.3565430f, C2 = 0.0848830f,
                C3 = -0.0110610f, C4 = 0.0005820f;
    f32x2 y = x * 0.70710678f;
    f32x2 t;
    t.x = fminf(fmaxf(y.x, -2.5f), 2.5f);
    t.y = fminf(fmaxf(y.y, -2.5f), 2.5f);
    f32x2 u = t * t;
    f32x2 p = u * C4 + C3;
    p = p * u + C2;
    p = p * u + C1;
    p = p * u + C0;
    f32x2 e = t * p;                 // ~erf(y)
    f32x2 h = x * 0.5f;
    return h * e + h;                // 0.5x(1+erf)
}

__device__ __forceinline__ float bilin(const float* __restrict__ img, float py, float px) {
    float y0f = floorf(py), x0f = floorf(px);
    float wy = py - y0f, wx = px - x0f;
    int y0 = (int)y0f, x0 = (int)x0f;
    int yc0 = min(max(y0, 0), Hh - 1), yc1 = min(max(y0 + 1, 0), Hh - 1);
    int xc0 = min(max(x0, 0), Ww - 1), xc1 = min(max(x0 + 1, 0), Ww - 1);
    bool vy0 = (unsigned)y0 < (unsigned)Hh, vy1 = (unsigned)(y0 + 1) < (unsigned)Hh;
    bool vx0 = (unsigned)x0 < (unsigned)Ww, vx1 = (unsigned)(x0 + 1) < (unsigned)Ww;
    const float* r0 = img + yc0 * Ww;
    const float* r1 = img + yc1 * Ww;
    float v00 = (vy0 && vx0) ? r0[xc0] : 0.0f;
    float v01 = (vy0 && vx1) ? r0[xc1] : 0.0f;
    float v10 = (vy1 && vx0) ? r1[xc0] : 0.0f;
    float v11 = (vy1 && vx1) ? r1[xc1] : 0.0f;
    return (1.0f - wy) * ((1.0f - wx) * v00 + wx * v01) +
           wy          * ((1.0f - wx) * v10 + wx * v11);
}

// ---- pre-pass: pack w2 A-frags (9 taps, 32x32x16) + w1 A-frags (2, 16x16x32) ----
// ws int4 [0,576)   : w2 frags: lane l31=co(m), elem j -> ci = lh*8+j, per tap
// ws int4 [576,704) : w1 frags: lane m=lane&15(co), k=(lane>>4)*8+j,
//                     k = 16*kyloc + 4*kx + c, ky = 2*t + kyloc;
//                     value = w1[co][c][ky][kx] (kx<3,c<3,ky<3); slot t=0,k=3 = b1[co]
__global__ void pack_w(const float* __restrict__ w2, const float* __restrict__ w1,
                       const float* __restrict__ b1, int* __restrict__ ws) {
    const int lane = threadIdx.x;            // 64 threads
    const int l31  = lane & 31;
    const int lh   = lane >> 5;
    for (int tap = 0; tap < 9; ++tap) {
        int pk[4];
        #pragma unroll
        for (int jj = 0; jj < 4; ++jj) {
            float v0 = (l31 < 18) ? w2[(l31 * 16 + lh * 8 + 2 * jj    ) * 9 + tap] : 0.0f;
            float v1 = (l31 < 18) ? w2[(l31 * 16 + lh * 8 + 2 * jj + 1) * 9 + tap] : 0.0f;
            pk[jj] = ((int)(unsigned short)f2bf(v0)) | ((int)f2bf(v1) << 16);
        }
        ((int4*)ws)[tap * 64 + lane] = make_int4(pk[0], pk[1], pk[2], pk[3]);
    }
    const int m  = lane & 15;
    const int kq = lane >> 4;
    for (int t = 0; t < 2; ++t) {
        int pk[4];
        #pragma unroll
        for (int jj = 0; jj < 4; ++jj) {
            float vv[2];
            #pragma unroll
            for (int h = 0; h < 2; ++h) {
                int k   = kq * 8 + 2 * jj + h;
                int kyl = k >> 4, kx = (k >> 2) & 3, c = k & 3;
                int ky  = 2 * t + kyl;
                float x = 0.0f;
                if (kx < 3 && c < 3 && ky < 3) x = w1[m * 27 + c * 9 + ky * 3 + kx];
                if (t == 0 && k == 3) x = b1[m];     // bias slot (reads const-1.0 channel)
                vv[h] = x;
            }
            pk[jj] = ((int)(unsigned short)f2bf(vv[0])) | ((int)f2bf(vv[1]) << 16);
        }
        ((int4*)ws)[576 + t * 64 + lane] = make_int4(pk[0], pk[1], pk[2], pk[3]);
    }
}

// LDS:
//   s_in   bf16 dup-entries [SIN_N][8] @ 0      (22400 B)
//          entry e (16B) = positions e,e+1, each (wind0,wind1,topo,1.0) bf16
//   s_feat bf16 [2][NFP][8] @ 22400             (40960 B)  conv1 out (conv2 B-matrix)
#define SMEM_BYTES (SIN_N * 16 + 2 * NFP * 16)   // 63360

__global__ __launch_bounds__(NTHREADS, 8) void residual_advection_fused(
    const float* __restrict__ pm25,   // (16,1,512,512)
    const float* __restrict__ wind,   // (16,2,512,512)
    const float* __restrict__ topo,   // (16,1,512,512)
    const float* __restrict__ b2,     // (18)
    const float* __restrict__ wt,     // (9)
    const int*   __restrict__ wsB,    // packed w2 + w1 A-fragments
    float* __restrict__ out)          // (16,1,512,512)
{
    __shared__ __align__(16) char smem[SMEM_BYTES];
    __bf16* s_in   = (__bf16*)smem;                  // dup entries, 16B each
    __bf16* s_feat = (__bf16*)(smem + SIN_N * 16);   // [2][NFP][8]

    const int tid = threadIdx.x;
    const int bb  = blockIdx.z;
    const int ty0 = blockIdx.y * TILE;
    const int tx0 = blockIdx.x * TILE;
    const bool edge = (ty0 == 0) || (ty0 == Hh - TILE) || (tx0 == 0) || (tx0 == Ww - TILE);

    const int lane = tid & 63;
    const int wv   = tid >> 6;       // 0..15
    const int l31  = lane & 31;
    const int lh   = lane >> 5;

    const bfrag* WF = (const bfrag*)wsB;

    // hoist conv1 weight A-frags (L2-hot; latency hidden under staging)
    bfrag w1f0 = WF[576 + lane];
    bfrag w1f1 = WF[640 + lane];

    // ---- P1: stage input halo, dup layout: pos idx -> entry[idx].lo, entry[idx-1].hi ----
    for (int idx = tid; idx < SIN_N; idx += NTHREADS) {
        float c0 = 0.0f, c1 = 0.0f, c2 = 0.0f;
        if (idx < 36 * S) {
            int r = idx / S, c = idx - r * S;
            if (!edge) {                              // interior: no bounds masks
                int g = (ty0 - 2 + r) * Ww + (tx0 - 2 + c);
                c0 = wind[(bb * 2 + 0) * HW_ + g];
                c1 = wind[(bb * 2 + 1) * HW_ + g];
                c2 = topo[bb * HW_ + g];
            } else {
                int gy = ty0 - 2 + r, gx = tx0 - 2 + c;
                if ((unsigned)gy < (unsigned)Hh && (unsigned)gx < (unsigned)Ww) {
                    int g = gy * Ww + gx;
                    c0 = wind[(bb * 2 + 0) * HW_ + g];
                    c1 = wind[(bb * 2 + 1) * HW_ + g];
                    c2 = topo[bb * HW_ + g];
                }
            }
        }
        bf4 v;
        v[0] = (__bf16)c0; v[1] = (__bf16)c1; v[2] = (__bf16)c2; v[3] = (__bf16)1.0f;
        *(bf4*)&s_in[idx * 8] = v;                       // entry idx, low 8B
        if (idx > 0) *(bf4*)&s_in[idx * 8 - 4] = v;      // entry idx-1, high 8B
    }
    __syncthreads();

    // ---- P2: conv1 via MFMA 16x16x32, A=w1 (m=co16), B=input rows (n=pos) ----
    // K = 2 kernel-rows x (4 kx x 4 ch); bias via const-1.0 channel slot.
    {
        const int n    = lane & 15;
        const int kq   = lane >> 4;
        const int qoff = (kq >> 1) * S + (kq & 1) * 2;   // kyloc row + kx-pair offset
        #pragma unroll
        for (int i = 0; i < 5; ++i) {
            const int p = (wv * 5 + i) * 16 + n;
            f32x4 acc;
            acc[0] = 0.0f; acc[1] = 0.0f; acc[2] = 0.0f; acc[3] = 0.0f;
            bfrag bx0 = *(const bfrag*)&s_in[(p + qoff) * 8];           // ky rows 0,1
            bfrag bx1 = *(const bfrag*)&s_in[(p + qoff + 2 * S) * 8];   // ky rows 2,(pad)
            acc = __builtin_amdgcn_mfma_f32_16x16x32_bf16(w1f0, bx0, acc, 0, 0, 0);
            acc = __builtin_amdgcn_mfma_f32_16x16x32_bf16(w1f1, bx1, acc, 0, 0, 0);
            // epilogue: gelu + (edge-only) validity mask, bf16 store of 4 co values
            f32x2 g0 = gelu_fast2(mk2(acc[0], acc[1]));
            f32x2 g1 = gelu_fast2(mk2(acc[2], acc[3]));
            if (edge) {
                int fy = p / S;
                int fx = p - fy * S;
                int gy = ty0 + fy - 1, gx = tx0 + fx - 1;
                float msk = ((unsigned)gy < (unsigned)Hh && (unsigned)gx < (unsigned)Ww)
                            ? 1.0f : 0.0f;
                g0 *= msk; g1 *= msk;
            }
            bf4 w4;
            w4[0] = (__bf16)g0.x; w4[1] = (__bf16)g0.y;
            w4[2] = (__bf16)g1.x; w4[3] = (__bf16)g1.y;
            // co-group kq: half = kq>>1, sub-slot = kq&1
            *(bf4*)&s_feat[((kq >> 1) * NFP + p) * 8 + (kq & 1) * 4] = w4;
        }
    }
    __syncthreads();

    // ---- P3: conv2 via MFMA 32x32x16, A=w2 (m=co18), B=feat (n=pixel) ----
    // Fragment sharing: chain a1's (ky,kx) fragment == chain a0's (ky+1,kx);
    // 12 unique ds_read_b128 (4 rows x 3 kx) instead of 18.
    ffrag a0, a1;
    #pragma unroll
    for (int r = 0; r < 16; ++r) { a0[r] = 0.0f; a1[r] = 0.0f; }
    {
        const int vb = (lh * NFP + (2 * wv) * S + l31) * 8;
        #pragma unroll
        for (int kx = 0; kx < 3; ++kx) {
            bfrag f0 = *(const bfrag*)&s_feat[vb + (0 * S + kx) * 8];
            bfrag f1 = *(const bfrag*)&s_feat[vb + (1 * S + kx) * 8];
            bfrag f2 = *(const bfrag*)&s_feat[vb + (2 * S + kx) * 8];
            bfrag f3 = *(const bfrag*)&s_feat[vb + (3 * S + kx) * 8];
            bfrag w0 = WF[(0 * 3 + kx) * 64 + lane];
            bfrag w1_ = WF[(1 * 3 + kx) * 64 + lane];
            bfrag w2_ = WF[(2 * 3 + kx) * 64 + lane];
            a0 = __builtin_amdgcn_mfma_f32_32x32x16_bf16(w0,  f0, a0, 0, 0, 0);
            a1 = __builtin_amdgcn_mfma_f32_32x32x16_bf16(w0,  f1, a1, 0, 0, 0);
            a0 = __builtin_amdgcn_mfma_f32_32x32x16_bf16(w1_, f1, a0, 0, 0, 0);
            a1 = __builtin_amdgcn_mfma_f32_32x32x16_bf16(w1_, f2, a1, 0, 0, 0);
            a0 = __builtin_amdgcn_mfma_f32_32x32x16_bf16(w2_, f2, a0, 0, 0, 0);
            a1 = __builtin_amdgcn_mfma_f32_32x32x16_bf16(w2_, f3, a1, 0, 0, 0);
        }
    }

    // ---- P4: lazy per-active-tap exchange, one bilinear sample per lane ----
    // C/D: col = pixel = l31, row = co = (reg&3)+8*(reg>>2)+4*lh.
    // Tap t rows (2t,2t+1) both live in half o=(t>>1)&1 at regs rg,rg+1.
    // Chain a0 = pixel row 2wv, chain a1 = row 2wv+1; lane outputs row 2wv+lh.
    {
        const float* img = pm25 + bb * HW_;
        const int py_i = ty0 + 2 * wv + lh;
        const int px_i = tx0 + l31;
        const float fy = (float)py_i, fx = (float)px_i;
        float o = 0.0f;
        #pragma unroll
        for (int t = 0; t < 9; ++t) {
            float wk = wt[t];                        // uniform -> scalar branch
            if (wk != 0.0f) {
                const int o_h = (t >> 1) & 1;                  // owner lane-half
                const int rg  = ((2 * t) & 3) + 4 * (t >> 2);  // dy reg; dx = rg+1
                float dy, dx;
                if (o_h == 0) {
                    float sy = __shfl_xor(a1[rg], 32);
                    float sx = __shfl_xor(a1[rg + 1], 32);
                    dy = lh ? sy : a0[rg];
                    dx = lh ? sx : a0[rg + 1];
                } else {
                    float sy = __shfl_xor(a0[rg], 32);
                    float sx = __shfl_xor(a0[rg + 1], 32);
                    dy = lh ? a1[rg] : sy;
                    dx = lh ? a1[rg + 1] : sx;
                }
                dy += b2[2 * t];
                dx += b2[2 * t + 1];
                float py = fy + (float)(t / 3 - 1) + dy;
                float px = fx + (float)(t % 3 - 1) + dx;
                o += wk * bilin(img, py, px);
            }
        }
        out[bb * HW_ + py_i * Ww + px_i] = o;
    }
}

extern "C" void kernel_launch(void* const* d_in, const int* in_sizes, int n_in,
                              void* d_out, int out_size, void* d_ws, size_t ws_size,
                              hipStream_t stream) {
    const float* pm25 = (const float*)d_in[0];
    const float* wind = (const float*)d_in[1];
    const float* topo = (const float*)d_in[2];
    const float* w1   = (const float*)d_in[3];
    const float* b1   = (const float*)d_in[4];
    const float* w2   = (const float*)d_in[5];
    const float* b2   = (const float*)d_in[6];
    const float* wt   = (const float*)d_in[7];
    float* o          = (float*)d_out;
    int*   wsB        = (int*)d_ws;   // 576+128 int4 = 11264 B

    pack_w<<<dim3(1), dim3(64), 0, stream>>>(w2, w1, b1, wsB);

    dim3 grid(Ww / TILE, Hh / TILE, Bn);
    residual_advection_fused<<<grid, dim3(NTHREADS), 0, stream>>>(
        pm25, wind, topo, b2, wt, wsB, o);
}

// Round 4
// 175.220 us; speedup vs baseline: 1.2600x; 1.0090x over previous
//
#include <hip/hip_runtime.h>
#include <math.h>

#define Bn 16
#define Hh 512
#define Ww 512
#define HW_ (Hh * Ww)
#define TW 32                // tile width
#define TH 16                // tile height
#define NTHREADS 512
#define S 37                 // unified grid stride (input halo & feat grids)
#define NROWS 20             // input halo rows (TH+4)
#define SIN_N 800            // staged entries: 20*37=740 valid + pad rows for ky3 reads
#define NFP 672              // feat positions per 8-ch half (42 tiles * 16)
#define NT 42                // conv1 position tiles of 16 (covers 18 rows * 37 cols)

typedef __bf16 bfrag __attribute__((ext_vector_type(8)));
typedef __bf16 bf4   __attribute__((ext_vector_type(4)));
typedef float  ffrag __attribute__((ext_vector_type(16)));
typedef float  f32x4 __attribute__((ext_vector_type(4)));
typedef float  f32x2 __attribute__((ext_vector_type(2)));

__device__ __forceinline__ short f2bf(float f) {           // RNE fp32 -> bf16 bits
    unsigned u = __float_as_uint(f);
    unsigned r = u + 0x7FFFu + ((u >> 16) & 1u);
    return (short)(r >> 16);
}

__device__ __forceinline__ f32x2 mk2(float a, float b) { f32x2 t; t.x = a; t.y = b; return t; }

// gelu exact-form via trans-free erf polynomial (same numerics as R3):
// gelu(x) = 0.5x(1+erf(x/sqrt2)); erf(y) ~= t*P(t^2), t = clamp(y,-2.5,2.5).
__device__ __forceinline__ f32x2 gelu_fast2(f32x2 x) {
    const float C0 = 1.1259890f, C1 = -0.3565430f, C2 = 0.0848830f,
                C3 = -0.0110610f, C4 = 0.0005820f;
    f32x2 y = x * 0.70710678f;
    f32x2 t;
    t.x = fminf(fmaxf(y.x, -2.5f), 2.5f);
    t.y = fminf(fmaxf(y.y, -2.5f), 2.5f);
    f32x2 u = t * t;
    f32x2 p = u * C4 + C3;
    p = p * u + C2;
    p = p * u + C1;
    p = p * u + C0;
    f32x2 e = t * p;                 // ~erf(y)
    f32x2 h = x * 0.5f;
    return h * e + h;                // 0.5x(1+erf)
}

__device__ __forceinline__ float bilin(const float* __restrict__ img, float py, float px) {
    float y0f = floorf(py), x0f = floorf(px);
    float wy = py - y0f, wx = px - x0f;
    int y0 = (int)y0f, x0 = (int)x0f;
    int yc0 = min(max(y0, 0), Hh - 1), yc1 = min(max(y0 + 1, 0), Hh - 1);
    int xc0 = min(max(x0, 0), Ww - 1), xc1 = min(max(x0 + 1, 0), Ww - 1);
    bool vy0 = (unsigned)y0 < (unsigned)Hh, vy1 = (unsigned)(y0 + 1) < (unsigned)Hh;
    bool vx0 = (unsigned)x0 < (unsigned)Ww, vx1 = (unsigned)(x0 + 1) < (unsigned)Ww;
    const float* r0 = img + yc0 * Ww;
    const float* r1 = img + yc1 * Ww;
    float v00 = (vy0 && vx0) ? r0[xc0] : 0.0f;
    float v01 = (vy0 && vx1) ? r0[xc1] : 0.0f;
    float v10 = (vy1 && vx0) ? r1[xc0] : 0.0f;
    float v11 = (vy1 && vx1) ? r1[xc1] : 0.0f;
    return (1.0f - wy) * ((1.0f - wx) * v00 + wx * v01) +
           wy          * ((1.0f - wx) * v10 + wx * v11);
}

// ---- pre-pass: pack w2 A-frags (9 taps, 32x32x16) + w1 A-frags (2, 16x16x32) ----
// ws int4 [0,576)   : w2 frags: lane l31=co(m), elem j -> ci = lh*8+j, per tap
// ws int4 [576,704) : w1 frags: lane m=lane&15(co), k=(lane>>4)*8+j,
//                     k = 16*kyloc + 4*kx + c, ky = 2*t + kyloc;
//                     value = w1[co][c][ky][kx] (kx<3,c<3,ky<3); slot t=0,k=3 = b1[co]
__global__ void pack_w(const float* __restrict__ w2, const float* __restrict__ w1,
                       const float* __restrict__ b1, int* __restrict__ ws) {
    const int lane = threadIdx.x;            // 64 threads
    const int l31  = lane & 31;
    const int lh   = lane >> 5;
    for (int tap = 0; tap < 9; ++tap) {
        int pk[4];
        #pragma unroll
        for (int jj = 0; jj < 4; ++jj) {
            float v0 = (l31 < 18) ? w2[(l31 * 16 + lh * 8 + 2 * jj    ) * 9 + tap] : 0.0f;
            float v1 = (l31 < 18) ? w2[(l31 * 16 + lh * 8 + 2 * jj + 1) * 9 + tap] : 0.0f;
            pk[jj] = ((int)(unsigned short)f2bf(v0)) | ((int)f2bf(v1) << 16);
        }
        ((int4*)ws)[tap * 64 + lane] = make_int4(pk[0], pk[1], pk[2], pk[3]);
    }
    const int m  = lane & 15;
    const int kq = lane >> 4;
    for (int t = 0; t < 2; ++t) {
        int pk[4];
        #pragma unroll
        for (int jj = 0; jj < 4; ++jj) {
            float vv[2];
            #pragma unroll
            for (int h = 0; h < 2; ++h) {
                int k   = kq * 8 + 2 * jj + h;
                int kyl = k >> 4, kx = (k >> 2) & 3, c = k & 3;
                int ky  = 2 * t + kyl;
                float x = 0.0f;
                if (kx < 3 && c < 3 && ky < 3) x = w1[m * 27 + c * 9 + ky * 3 + kx];
                if (t == 0 && k == 3) x = b1[m];     // bias slot (reads const-1.0 channel)
                vv[h] = x;
            }
            pk[jj] = ((int)(unsigned short)f2bf(vv[0])) | ((int)f2bf(vv[1]) << 16);
        }
        ((int4*)ws)[576 + t * 64 + lane] = make_int4(pk[0], pk[1], pk[2], pk[3]);
    }
}

// LDS (34304 B -> 4 blocks/CU = 4 independent 8-wave barrier domains):
//   s_in   bf16 dup-entries [SIN_N][8] @ 0       (12800 B)
//          entry e (16B) = positions e,e+1, each (wind0,wind1,topo,1.0) bf16
//   s_feat bf16 [2][NFP][8] @ 12800              (21504 B)  conv1 out (conv2 B-matrix)
#define SMEM_BYTES (SIN_N * 16 + 2 * NFP * 16)   // 34304

__global__ __launch_bounds__(NTHREADS, 8) void residual_advection_fused(
    const float* __restrict__ pm25,   // (16,1,512,512)
    const float* __restrict__ wind,   // (16,2,512,512)
    const float* __restrict__ topo,   // (16,1,512,512)
    const float* __restrict__ b2,     // (18)
    const float* __restrict__ wt,     // (9)
    const int*   __restrict__ wsB,    // packed w2 + w1 A-fragments
    float* __restrict__ out)          // (16,1,512,512)
{
    __shared__ __align__(16) char smem[SMEM_BYTES];
    __bf16* s_in   = (__bf16*)smem;                  // dup entries, 16B each
    __bf16* s_feat = (__bf16*)(smem + SIN_N * 16);   // [2][NFP][8]

    const int tid = threadIdx.x;
    const int bb  = blockIdx.z;
    const int ty0 = blockIdx.y * TH;
    const int tx0 = blockIdx.x * TW;
    const bool edge = (ty0 == 0) || (ty0 == Hh - TH) || (tx0 == 0) || (tx0 == Ww - TW);

    const int lane = tid & 63;
    const int wv   = tid >> 6;       // 0..7
    const int l31  = lane & 31;
    const int lh   = lane >> 5;

    const bfrag* WF = (const bfrag*)wsB;

    // hoist conv1 weight A-frags (L2-hot; latency hidden under staging)
    bfrag w1f0 = WF[576 + lane];
    bfrag w1f1 = WF[640 + lane];

    // ---- P1: stage input halo, dup layout: pos idx -> entry[idx].lo, entry[idx-1].hi ----
    for (int idx = tid; idx < SIN_N; idx += NTHREADS) {
        float c0 = 0.0f, c1 = 0.0f, c2 = 0.0f;
        if (idx < NROWS * S) {
            int r = idx / S, c = idx - r * S;
            if (!edge) {                              // interior: no bounds masks
                int g = (ty0 - 2 + r) * Ww + (tx0 - 2 + c);
                c0 = wind[(bb * 2 + 0) * HW_ + g];
                c1 = wind[(bb * 2 + 1) * HW_ + g];
                c2 = topo[bb * HW_ + g];
            } else {
                int gy = ty0 - 2 + r, gx = tx0 - 2 + c;
                if ((unsigned)gy < (unsigned)Hh && (unsigned)gx < (unsigned)Ww) {
                    int g = gy * Ww + gx;
                    c0 = wind[(bb * 2 + 0) * HW_ + g];
                    c1 = wind[(bb * 2 + 1) * HW_ + g];
                    c2 = topo[bb * HW_ + g];
                }
            }
        }
        bf4 v;
        v[0] = (__bf16)c0; v[1] = (__bf16)c1; v[2] = (__bf16)c2; v[3] = (__bf16)1.0f;
        *(bf4*)&s_in[idx * 8] = v;                       // entry idx, low 8B
        if (idx > 0) *(bf4*)&s_in[idx * 8 - 4] = v;      // entry idx-1, high 8B
    }
    __syncthreads();

    // ---- P2: conv1 via MFMA 16x16x32, A=w1 (m=co16), B=input rows (n=pos) ----
    // K = 2 kernel-rows x (4 kx x 4 ch); bias via const-1.0 channel slot.
    {
        const int n    = lane & 15;
        const int kq   = lane >> 4;
        const int qoff = (kq >> 1) * S + (kq & 1) * 2;   // kyloc row + kx-pair offset
        for (int tt = wv; tt < NT; tt += 8) {
            const int p = tt * 16 + n;
            f32x4 acc;
            acc[0] = 0.0f; acc[1] = 0.0f; acc[2] = 0.0f; acc[3] = 0.0f;
            bfrag bx0 = *(const bfrag*)&s_in[(p + qoff) * 8];           // ky rows 0,1
            bfrag bx1 = *(const bfrag*)&s_in[(p + qoff + 2 * S) * 8];   // ky rows 2,(pad)
            acc = __builtin_amdgcn_mfma_f32_16x16x32_bf16(w1f0, bx0, acc, 0, 0, 0);
            acc = __builtin_amdgcn_mfma_f32_16x16x32_bf16(w1f1, bx1, acc, 0, 0, 0);
            // epilogue: gelu + (edge-only) validity mask, bf16 store of 4 co values
            f32x2 g0 = gelu_fast2(mk2(acc[0], acc[1]));
            f32x2 g1 = gelu_fast2(mk2(acc[2], acc[3]));
            if (edge) {
                int fy = p / S;
                int fx = p - fy * S;
                int gy = ty0 + fy - 1, gx = tx0 + fx - 1;
                float msk = ((unsigned)gy < (unsigned)Hh && (unsigned)gx < (unsigned)Ww)
                            ? 1.0f : 0.0f;
                g0 *= msk; g1 *= msk;
            }
            bf4 w4;
            w4[0] = (__bf16)g0.x; w4[1] = (__bf16)g0.y;
            w4[2] = (__bf16)g1.x; w4[3] = (__bf16)g1.y;
            // co-group kq: half = kq>>1, sub-slot = kq&1
            *(bf4*)&s_feat[((kq >> 1) * NFP + p) * 8 + (kq & 1) * 4] = w4;
        }
    }
    __syncthreads();

    // ---- P3: conv2 via MFMA 32x32x16, A=w2 (m=co18), B=feat (n=pixel) ----
    // Fragment sharing: chain a1's (ky,kx) fragment == chain a0's (ky+1,kx);
    // 12 unique ds_read_b128 (4 rows x 3 kx) instead of 18.
    ffrag a0, a1;
    #pragma unroll
    for (int r = 0; r < 16; ++r) { a0[r] = 0.0f; a1[r] = 0.0f; }
    {
        const int vb = (lh * NFP + (2 * wv) * S + l31) * 8;
        #pragma unroll
        for (int kx = 0; kx < 3; ++kx) {
            bfrag f0 = *(const bfrag*)&s_feat[vb + (0 * S + kx) * 8];
            bfrag f1 = *(const bfrag*)&s_feat[vb + (1 * S + kx) * 8];
            bfrag f2 = *(const bfrag*)&s_feat[vb + (2 * S + kx) * 8];
            bfrag f3 = *(const bfrag*)&s_feat[vb + (3 * S + kx) * 8];
            bfrag w0 = WF[(0 * 3 + kx) * 64 + lane];
            bfrag w1_ = WF[(1 * 3 + kx) * 64 + lane];
            bfrag w2_ = WF[(2 * 3 + kx) * 64 + lane];
            a0 = __builtin_amdgcn_mfma_f32_32x32x16_bf16(w0,  f0, a0, 0, 0, 0);
            a1 = __builtin_amdgcn_mfma_f32_32x32x16_bf16(w0,  f1, a1, 0, 0, 0);
            a0 = __builtin_amdgcn_mfma_f32_32x32x16_bf16(w1_, f1, a0, 0, 0, 0);
            a1 = __builtin_amdgcn_mfma_f32_32x32x16_bf16(w1_, f2, a1, 0, 0, 0);
            a0 = __builtin_amdgcn_mfma_f32_32x32x16_bf16(w2_, f2, a0, 0, 0, 0);
            a1 = __builtin_amdgcn_mfma_f32_32x32x16_bf16(w2_, f3, a1, 0, 0, 0);
        }
    }

    // ---- P4: lazy per-active-tap exchange, one bilinear sample per lane ----
    // C/D: col = pixel = l31, row = co = (reg&3)+8*(reg>>2)+4*lh.
    // Tap t rows (2t,2t+1) both live in half o=(t>>1)&1 at regs rg,rg+1.
    // Chain a0 = pixel row 2wv, chain a1 = row 2wv+1; lane outputs row 2wv+lh.
    {
        const float* img = pm25 + bb * HW_;
        const int py_i = ty0 + 2 * wv + lh;
        const int px_i = tx0 + l31;
        const float fy = (float)py_i, fx = (float)px_i;
        float o = 0.0f;
        #pragma unroll
        for (int t = 0; t < 9; ++t) {
            float wk = wt[t];                        // uniform -> scalar branch
            if (wk != 0.0f) {
                const int o_h = (t >> 1) & 1;                  // owner lane-half
                const int rg  = ((2 * t) & 3) + 4 * (t >> 2);  // dy reg; dx = rg+1
                float dy, dx;
                if (o_h == 0) {
                    float sy = __shfl_xor(a1[rg], 32);
                    float sx = __shfl_xor(a1[rg + 1], 32);
                    dy = lh ? sy : a0[rg];
                    dx = lh ? sx : a0[rg + 1];
                } else {
                    float sy = __shfl_xor(a0[rg], 32);
                    float sx = __shfl_xor(a0[rg + 1], 32);
                    dy = lh ? a1[rg] : sy;
                    dx = lh ? a1[rg + 1] : sx;
                }
                dy += b2[2 * t];
                dx += b2[2 * t + 1];
                float py = fy + (float)(t / 3 - 1) + dy;
                float px = fx + (float)(t % 3 - 1) + dx;
                o += wk * bilin(img, py, px);
            }
        }
        out[bb * HW_ + py_i * Ww + px_i] = o;
    }
}

extern "C" void kernel_launch(void* const* d_in, const int* in_sizes, int n_in,
                              void* d_out, int out_size, void* d_ws, size_t ws_size,
                              hipStream_t stream) {
    const float* pm25 = (const float*)d_in[0];
    const float* wind = (const float*)d_in[1];
    const float* topo = (const float*)d_in[2];
    const float* w1   = (const float*)d_in[3];
    const float* b1   = (const float*)d_in[4];
    const float* w2   = (const float*)d_in[5];
    const float* b2   = (const float*)d_in[6];
    const float* wt   = (const float*)d_in[7];
    float* o          = (float*)d_out;
    int*   wsB        = (int*)d_ws;   // 576+128 int4 = 11264 B

    pack_w<<<dim3(1), dim3(64), 0, stream>>>(w2, w1, b1, wsB);

    dim3 grid(Ww / TW, Hh / TH, Bn);
    residual_advection_fused<<<grid, dim3(NTHREADS), 0, stream>>>(
        pm25, wind, topo, b2, wt, wsB, o);
}